// Round 1
// baseline (223.707 us; speedup 1.0000x reference)
//
#include <hip/hip_runtime.h>
#include <hip/hip_bf16.h>

// LayerNorm over last dim W=256 for (B=8, C=128, H=128, W=256) fp32,
// then per-channel affine: out = (x - mean)/sqrt(var+eps) * gain[c] + bias[c].
//
// One wave per row: 64 lanes x float4 = 256 elements. Wave-level shfl_xor
// butterfly reduction for sum / sumsq. Memory-bound kernel: 268 MB total
// traffic, roofline ~43 us at 6.3 TB/s.

#define W_DIM 256
#define H_DIM 128
#define C_DIM 128
#define EPS 1e-8f

__global__ __launch_bounds__(256) void tLNv2_kernel(
    const float* __restrict__ inp,
    const float* __restrict__ gain,
    const float* __restrict__ bias,
    float* __restrict__ out)
{
    const int lane = threadIdx.x & 63;
    const int wave = threadIdx.x >> 6;
    const long long row = (long long)blockIdx.x * 4 + wave;  // 4 waves/block

    const float4* __restrict__ in4 = (const float4*)(inp + row * W_DIM);
    float4 v = in4[lane];

    float s  = v.x + v.y + v.z + v.w;
    float sq = v.x * v.x + v.y * v.y + v.z * v.z + v.w * v.w;

    // 64-lane butterfly reduction (all lanes end with the full sum)
    #pragma unroll
    for (int off = 1; off < 64; off <<= 1) {
        s  += __shfl_xor(s,  off, 64);
        sq += __shfl_xor(sq, off, 64);
    }

    const float mean = s * (1.0f / (float)W_DIM);
    const float var  = sq * (1.0f / (float)W_DIM) - mean * mean;
    const float rstd = rsqrtf(var + EPS);

    // row = b*C*H + c*H + h ; H=128, C=128
    const int c = (int)((row >> 7) & (C_DIM - 1));
    const float g = gain[c];
    const float b = bias[c];

    float4 o;
    o.x = (v.x - mean) * rstd * g + b;
    o.y = (v.y - mean) * rstd * g + b;
    o.z = (v.z - mean) * rstd * g + b;
    o.w = (v.w - mean) * rstd * g + b;

    ((float4*)(out + row * W_DIM))[lane] = o;
}

extern "C" void kernel_launch(void* const* d_in, const int* in_sizes, int n_in,
                              void* d_out, int out_size, void* d_ws, size_t ws_size,
                              hipStream_t stream)
{
    const float* inp  = (const float*)d_in[0];
    const float* gain = (const float*)d_in[1];
    const float* bias = (const float*)d_in[2];
    float* out = (float*)d_out;

    const long long rows = (long long)in_sizes[0] / W_DIM;  // 131072
    const int blocks = (int)(rows / 4);                      // 4 waves per block

    tLNv2_kernel<<<blocks, 256, 0, stream>>>(inp, gain, bias, out);
}